// Round 1
// baseline (143.724 us; speedup 1.0000x reference)
//
#include <hip/hip_runtime.h>
#include <stdint.h>

#define N_ROWS 4096
#define D_DIM  1024
#define N_CAND 8192
#define TEMP_INV 20.0f

#define BM 128
#define BN 128
#define BK 64

typedef __attribute__((ext_vector_type(8))) _Float16 f16x8;
typedef __attribute__((ext_vector_type(4))) float    f32x4;
typedef __attribute__((ext_vector_type(4))) unsigned short us4;

using gvoid = __attribute__((address_space(1))) void;
using lvoid = __attribute__((address_space(3))) void;

__device__ __forceinline__ unsigned short f2h_bits(float f) {
  _Float16 h = (_Float16)f;
  return __builtin_bit_cast(unsigned short, h);
}

// ---------------------------------------------------------------------------
// Kernel 1: normalize rows, convert to fp16, pack cand=[P;N]; zero rowsum.
// One 256-thread block per row (3*4096 blocks). float4 loads (16B/lane).
// ---------------------------------------------------------------------------
__global__ __launch_bounds__(256) void prep_kernel(
    const float* __restrict__ s, const float* __restrict__ p,
    const float* __restrict__ ng, unsigned short* __restrict__ s_h,
    unsigned short* __restrict__ cand_h, float* __restrict__ rowsum) {
  const int row = blockIdx.x;
  const int t = threadIdx.x;
  const float* src;
  unsigned short* dst;
  if (row < N_ROWS) {
    src = s + (size_t)row * D_DIM;
    dst = s_h + (size_t)row * D_DIM;
  } else if (row < 2 * N_ROWS) {
    src = p + (size_t)(row - N_ROWS) * D_DIM;
    dst = cand_h + (size_t)(row - N_ROWS) * D_DIM;
  } else {
    src = ng + (size_t)(row - 2 * N_ROWS) * D_DIM;
    dst = cand_h + (size_t)(row - N_ROWS) * D_DIM;  // rows 4096..8191 of cand
  }

  float4 v = reinterpret_cast<const float4*>(src)[t];
  float ss = v.x * v.x + v.y * v.y + v.z * v.z + v.w * v.w;
#pragma unroll
  for (int m = 32; m >= 1; m >>= 1) ss += __shfl_xor(ss, m, 64);
  __shared__ float red[4];
  const int w = t >> 6, l = t & 63;
  if (l == 0) red[w] = ss;
  __syncthreads();
  const float tot = red[0] + red[1] + red[2] + red[3];
  const float scale = 1.0f / fmaxf(sqrtf(tot), 1e-8f);

  us4 o;
  o[0] = f2h_bits(v.x * scale);
  o[1] = f2h_bits(v.y * scale);
  o[2] = f2h_bits(v.z * scale);
  o[3] = f2h_bits(v.w * scale);
  reinterpret_cast<us4*>(dst)[t] = o;

  if (t == 0 && row < N_ROWS) rowsum[row] = 0.0f;
}

// ---------------------------------------------------------------------------
// Kernel 2: fused GEMM + exp-rowsum. 128x128 tile, BK=64, 4 waves (2x2),
// each wave a 64x64 sub-tile via 4x4 fragments of mfma_f32_16x16x32_f16.
// global_load_lds width=16 with XOR-swizzled source; swizzled ds_read_b128.
// Epilogue: rowsum[i] += sum_j exp(sim[i][j] - 20); diagonal -> pos[i].
// ---------------------------------------------------------------------------
__global__ __launch_bounds__(256) void gemm_lse_kernel(
    const unsigned short* __restrict__ s_h,
    const unsigned short* __restrict__ cand_h,
    float* __restrict__ rowsum, float* __restrict__ pos) {
  __shared__ __align__(16) unsigned char lds[2 * BM * BK * 2];  // A(16K)+B(16K)
  unsigned char* ldsA = lds;
  unsigned char* ldsB = lds + BM * BK * 2;

  const int t = threadIdx.x;
  const int w = t >> 6;
  const int l = t & 63;
  const int g = l >> 4;    // 16-lane group (k-slice)
  const int rl = l & 15;   // lane within group
  const int rowBase = blockIdx.y * BM;
  const int colBase = blockIdx.x * BN;
  const int wr = (w >> 1) * 64;  // wave's row offset in tile
  const int wc = (w & 1) * 64;   // wave's col offset in tile

  f32x4 acc[4][4] = {};

  for (int kt = 0; kt < D_DIM; kt += BK) {
    // ---- stage A,B tiles: 1024 16B-slots each, 4 per thread per matrix ----
#pragma unroll
    for (int it = 0; it < 4; ++it) {
      const int slot = it * 256 + t;         // 0..1023, == wave-base + lane
      const int r = slot >> 3;               // tile row (128B rows, 8 slots)
      const int scl = (slot & 7) ^ (r & 7);  // inverse-swizzled logical slot
      const unsigned short* gA =
          s_h + (size_t)(rowBase + r) * D_DIM + kt + scl * 8;
      const unsigned short* gB =
          cand_h + (size_t)(colBase + r) * D_DIM + kt + scl * 8;
      unsigned char* dA = ldsA + (size_t)(it * 256 + (w << 6)) * 16;  // uniform
      unsigned char* dB = ldsB + (size_t)(it * 256 + (w << 6)) * 16;
      __builtin_amdgcn_global_load_lds((const gvoid*)gA, (lvoid*)dA, 16, 0, 0);
      __builtin_amdgcn_global_load_lds((const gvoid*)gB, (lvoid*)dB, 16, 0, 0);
    }
    asm volatile("s_waitcnt vmcnt(0)" ::: "memory");
    __syncthreads();

    // ---- compute: 2 x (K=32) halves, 16 MFMA each ----
#pragma unroll
    for (int kk = 0; kk < 2; ++kk) {
      f16x8 af[4], bf[4];
#pragma unroll
      for (int m = 0; m < 4; ++m) {
        const int r = wr + m * 16 + rl;
        const int scs = (kk * 4 + g) ^ (r & 7);  // swizzled slot
        af[m] = *reinterpret_cast<const f16x8*>(ldsA + r * (BK * 2) + scs * 16);
      }
#pragma unroll
      for (int n = 0; n < 4; ++n) {
        const int r = wc + n * 16 + rl;
        const int scs = (kk * 4 + g) ^ (r & 7);
        bf[n] = *reinterpret_cast<const f16x8*>(ldsB + r * (BK * 2) + scs * 16);
      }
#pragma unroll
      for (int m = 0; m < 4; ++m)
#pragma unroll
        for (int n = 0; n < 4; ++n)
          acc[m][n] =
              __builtin_amdgcn_mfma_f32_16x16x32_f16(af[m], bf[n], acc[m][n],
                                                     0, 0, 0);
    }
    __syncthreads();
  }

  // ---- epilogue: sim = acc*20; cosine<=1 so sim<=20 — fixed-max logsumexp.
  // C/D layout: col = l&15, row = (l>>4)*4 + reg.
#pragma unroll
  for (int m = 0; m < 4; ++m) {
#pragma unroll
    for (int j = 0; j < 4; ++j) {
      const int rowg = rowBase + wr + m * 16 + g * 4 + j;
      float sm = 0.0f;
#pragma unroll
      for (int n = 0; n < 4; ++n) {
        const int colg = colBase + wc + n * 16 + rl;
        const float simv = acc[m][n][j] * TEMP_INV;
        if (colg == rowg) pos[rowg] = simv;  // diagonal logit (exactly sim[i,i])
        sm += __expf(simv - TEMP_INV);
      }
      // reduce over the 16 lanes (rl) sharing this row
      sm += __shfl_xor(sm, 1, 64);
      sm += __shfl_xor(sm, 2, 64);
      sm += __shfl_xor(sm, 4, 64);
      sm += __shfl_xor(sm, 8, 64);
      if (rl == 0) atomicAdd(&rowsum[rowg], sm);
    }
  }
}

// ---------------------------------------------------------------------------
// Kernel 3: loss = mean(20 + log(rowsum) - pos)
// ---------------------------------------------------------------------------
__global__ __launch_bounds__(1024) void loss_kernel(
    const float* __restrict__ rowsum, const float* __restrict__ pos,
    float* __restrict__ out) {
  const int t = threadIdx.x;
  float acc = 0.0f;
  for (int i = t; i < N_ROWS; i += 1024)
    acc += TEMP_INV + logf(rowsum[i]) - pos[i];
#pragma unroll
  for (int m = 32; m >= 1; m >>= 1) acc += __shfl_xor(acc, m, 64);
  __shared__ float red[16];
  const int w = t >> 6, l = t & 63;
  if (l == 0) red[w] = acc;
  __syncthreads();
  if (t == 0) {
    float tot = 0.0f;
#pragma unroll
    for (int i = 0; i < 16; ++i) tot += red[i];
    out[0] = tot / (float)N_ROWS;
  }
}

// ---------------------------------------------------------------------------
extern "C" void kernel_launch(void* const* d_in, const int* in_sizes, int n_in,
                              void* d_out, int out_size, void* d_ws,
                              size_t ws_size, hipStream_t stream) {
  (void)in_sizes; (void)n_in; (void)out_size; (void)ws_size;
  const float* s = (const float*)d_in[0];
  const float* p = (const float*)d_in[1];
  const float* ng = (const float*)d_in[2];

  unsigned short* s_h = (unsigned short*)d_ws;                    // 8 MB
  unsigned short* cand_h = s_h + (size_t)N_ROWS * D_DIM;          // 16 MB
  float* rowsum = (float*)(cand_h + (size_t)N_CAND * D_DIM);      // 16 KB
  float* pos = rowsum + N_ROWS;                                   // 16 KB
  float* out = (float*)d_out;

  prep_kernel<<<dim3(3 * N_ROWS), dim3(256), 0, stream>>>(s, p, ng, s_h,
                                                          cand_h, rowsum);
  gemm_lse_kernel<<<dim3(N_CAND / BN, N_ROWS / BM), dim3(256), 0, stream>>>(
      s_h, cand_h, rowsum, pos);
  loss_kernel<<<dim3(1), dim3(1024), 0, stream>>>(rowsum, pos, out);
}

// Round 2
// 113.287 us; speedup vs baseline: 1.2687x; 1.2687x over previous
//
#include <hip/hip_runtime.h>
#include <stdint.h>

#define N_ROWS 4096
#define D_DIM  1024
#define N_CAND 8192
#define TEMP_INV 20.0f

#define BM 256
#define BN 256
#define BK 64
#define NTILES (D_DIM / BK)  // 16

typedef __attribute__((ext_vector_type(8))) _Float16 f16x8;
typedef __attribute__((ext_vector_type(4))) float    f32x4;
typedef __attribute__((ext_vector_type(4))) unsigned short us4;

using gvoid = __attribute__((address_space(1))) void;
using lvoid = __attribute__((address_space(3))) void;

__device__ __forceinline__ unsigned short f2h_bits(float f) {
  _Float16 h = (_Float16)f;
  return __builtin_bit_cast(unsigned short, h);
}

// ---------------------------------------------------------------------------
// Kernel 1: normalize rows, convert to fp16, pack cand=[P;N]; zero rowsum.
// ---------------------------------------------------------------------------
__global__ __launch_bounds__(256) void prep_kernel(
    const float* __restrict__ s, const float* __restrict__ p,
    const float* __restrict__ ng, unsigned short* __restrict__ s_h,
    unsigned short* __restrict__ cand_h, float* __restrict__ rowsum) {
  const int row = blockIdx.x;
  const int t = threadIdx.x;
  const float* src;
  unsigned short* dst;
  if (row < N_ROWS) {
    src = s + (size_t)row * D_DIM;
    dst = s_h + (size_t)row * D_DIM;
  } else if (row < 2 * N_ROWS) {
    src = p + (size_t)(row - N_ROWS) * D_DIM;
    dst = cand_h + (size_t)(row - N_ROWS) * D_DIM;
  } else {
    src = ng + (size_t)(row - 2 * N_ROWS) * D_DIM;
    dst = cand_h + (size_t)(row - N_ROWS) * D_DIM;
  }

  float4 v = reinterpret_cast<const float4*>(src)[t];
  float ss = v.x * v.x + v.y * v.y + v.z * v.z + v.w * v.w;
#pragma unroll
  for (int m = 32; m >= 1; m >>= 1) ss += __shfl_xor(ss, m, 64);
  __shared__ float red[4];
  const int w = t >> 6, l = t & 63;
  if (l == 0) red[w] = ss;
  __syncthreads();
  const float tot = red[0] + red[1] + red[2] + red[3];
  const float scale = 1.0f / fmaxf(sqrtf(tot), 1e-8f);

  us4 o;
  o[0] = f2h_bits(v.x * scale);
  o[1] = f2h_bits(v.y * scale);
  o[2] = f2h_bits(v.z * scale);
  o[3] = f2h_bits(v.w * scale);
  reinterpret_cast<us4*>(dst)[t] = o;

  if (t == 0 && row < N_ROWS) rowsum[row] = 0.0f;
}

// ---------------------------------------------------------------------------
// Kernel 2: fused GEMM + exp-rowsum. 256x256 tile, BK=64, 8 waves (2Mx4N),
// double-buffered LDS (128 KiB), raw s_barrier + counted vmcnt(8) so one
// full tile's global_load_lds stays in flight across the next tile's MFMAs.
// XOR slot-swizzle on LDS (inverse-swizzled global source). Per-wave 128x64
// output = 8x4 fragments of mfma_f32_16x16x32_f16; 4 sub-phases per K-tile
// with setprio(1) around each 16-MFMA cluster.
// ---------------------------------------------------------------------------
__global__ __launch_bounds__(512, 2) void gemm_lse_kernel(
    const unsigned short* __restrict__ s_h,
    const unsigned short* __restrict__ cand_h,
    float* __restrict__ rowsum, float* __restrict__ pos) {
  __shared__ __align__(16) unsigned char lds[2 * 2 * BM * BK * 2];  // 128 KiB

  const int t = threadIdx.x;
  const int w = t >> 6;
  const int l = t & 63;
  const int g = l >> 4;   // k-slice group
  const int rl = l & 15;  // lane within group
  const int wm = w >> 2;  // 0..1  (wave's M half)
  const int wn = w & 3;   // 0..3  (wave's N quarter)
  const int rowBase = blockIdx.y * BM;
  const int colBase = blockIdx.x * BN;

  f32x4 acc[8][4] = {};

  // stage one K-tile (A: 256x64, B: 256x64) into buf; 8 loads/thread.
  auto stage = [&](int kt, int buf) {
    unsigned char* dA = lds + buf * 65536;
    unsigned char* dB = lds + buf * 65536 + 32768;
#pragma unroll
    for (int it = 0; it < 4; ++it) {
      const int slot = it * 512 + t;          // 0..2047
      const int r = slot >> 3;                // tile row (8 x 16B slots/row)
      const int scl = (slot & 7) ^ (r & 7);   // inverse-swizzled source slot
      const unsigned short* gA =
          s_h + (size_t)(rowBase + r) * D_DIM + kt + scl * 8;
      const unsigned short* gB =
          cand_h + (size_t)(colBase + r) * D_DIM + kt + scl * 8;
      unsigned char* pA = dA + (size_t)(it * 512 + w * 64) * 16;  // wave-uniform
      unsigned char* pB = dB + (size_t)(it * 512 + w * 64) * 16;
      __builtin_amdgcn_global_load_lds((const gvoid*)gA, (lvoid*)pA, 16, 0, 0);
      __builtin_amdgcn_global_load_lds((const gvoid*)gB, (lvoid*)pB, 16, 0, 0);
    }
  };

  // compute one K-tile from buf: 4 phases of 16 MFMA.
  auto compute = [&](int buf) {
    unsigned char* A = lds + buf * 65536;
    unsigned char* B = lds + buf * 65536 + 32768;
#pragma unroll
    for (int mh = 0; mh < 2; ++mh) {
      f16x8 af[4][2];
#pragma unroll
      for (int m2 = 0; m2 < 4; ++m2) {
        const int r = wm * 128 + (mh * 4 + m2) * 16 + rl;
#pragma unroll
        for (int kk = 0; kk < 2; ++kk) {
          const int sl = (kk * 4 + g) ^ (r & 7);
          af[m2][kk] =
              *reinterpret_cast<const f16x8*>(A + r * (BK * 2) + sl * 16);
        }
      }
#pragma unroll
      for (int nh = 0; nh < 2; ++nh) {
        f16x8 bf[2][2];
#pragma unroll
        for (int n2 = 0; n2 < 2; ++n2) {
          const int r = wn * 64 + (nh * 2 + n2) * 16 + rl;
#pragma unroll
          for (int kk = 0; kk < 2; ++kk) {
            const int sl = (kk * 4 + g) ^ (r & 7);
            bf[n2][kk] =
                *reinterpret_cast<const f16x8*>(B + r * (BK * 2) + sl * 16);
          }
        }
        __builtin_amdgcn_s_setprio(1);
#pragma unroll
        for (int m2 = 0; m2 < 4; ++m2)
#pragma unroll
          for (int n2 = 0; n2 < 2; ++n2)
#pragma unroll
            for (int kk = 0; kk < 2; ++kk)
              acc[mh * 4 + m2][nh * 2 + n2] =
                  __builtin_amdgcn_mfma_f32_16x16x32_f16(
                      af[m2][kk], bf[n2][kk], acc[mh * 4 + m2][nh * 2 + n2],
                      0, 0, 0);
        __builtin_amdgcn_s_setprio(0);
      }
    }
  };

  // prologue: tiles 0,1 in flight; wait tile 0 only.
  stage(0, 0);
  stage(BK, 1);
  asm volatile("s_waitcnt vmcnt(8)" ::: "memory");
  __builtin_amdgcn_s_barrier();

  for (int tI = 0; tI < NTILES; ++tI) {
    const int c = tI & 1;
    compute(c);
    __builtin_amdgcn_s_barrier();           // all waves done reading buf[c]
    __builtin_amdgcn_sched_barrier(0);
    if (tI + 2 < NTILES) {
      stage((tI + 2) * BK, c);              // overwrite buf[c] for tile t+2
      asm volatile("s_waitcnt vmcnt(8)" ::: "memory");  // tile t+1 landed
    } else {
      asm volatile("s_waitcnt vmcnt(0)" ::: "memory");  // tail drain
    }
    __builtin_amdgcn_sched_barrier(0);
    __builtin_amdgcn_s_barrier();           // buf[c^1] ready for next iter
  }

  // epilogue: sim = acc*20, cosine<=1 so fixed-max logsumexp at 20.
  // C/D layout: col = l&15, row = (l>>4)*4 + reg.
#pragma unroll
  for (int m = 0; m < 8; ++m) {
#pragma unroll
    for (int j = 0; j < 4; ++j) {
      const int rowg = rowBase + wm * 128 + m * 16 + g * 4 + j;
      float sm = 0.0f;
#pragma unroll
      for (int n = 0; n < 4; ++n) {
        const int colg = colBase + wn * 64 + n * 16 + rl;
        const float simv = acc[m][n][j] * TEMP_INV;
        if (colg == rowg) pos[rowg] = simv;
        sm += __expf(simv - TEMP_INV);
      }
      sm += __shfl_xor(sm, 1, 64);
      sm += __shfl_xor(sm, 2, 64);
      sm += __shfl_xor(sm, 4, 64);
      sm += __shfl_xor(sm, 8, 64);
      if (rl == 0) atomicAdd(&rowsum[rowg], sm);
    }
  }
}

// ---------------------------------------------------------------------------
// Kernel 3: loss = mean(20 + log(rowsum) - pos)
// ---------------------------------------------------------------------------
__global__ __launch_bounds__(1024) void loss_kernel(
    const float* __restrict__ rowsum, const float* __restrict__ pos,
    float* __restrict__ out) {
  const int t = threadIdx.x;
  float acc = 0.0f;
  for (int i = t; i < N_ROWS; i += 1024)
    acc += TEMP_INV + logf(rowsum[i]) - pos[i];
#pragma unroll
  for (int m = 32; m >= 1; m >>= 1) acc += __shfl_xor(acc, m, 64);
  __shared__ float red[16];
  const int w = t >> 6, l = t & 63;
  if (l == 0) red[w] = acc;
  __syncthreads();
  if (t == 0) {
    float tot = 0.0f;
#pragma unroll
    for (int i = 0; i < 16; ++i) tot += red[i];
    out[0] = tot / (float)N_ROWS;
  }
}

// ---------------------------------------------------------------------------
extern "C" void kernel_launch(void* const* d_in, const int* in_sizes, int n_in,
                              void* d_out, int out_size, void* d_ws,
                              size_t ws_size, hipStream_t stream) {
  (void)in_sizes; (void)n_in; (void)out_size; (void)ws_size;
  const float* s = (const float*)d_in[0];
  const float* p = (const float*)d_in[1];
  const float* ng = (const float*)d_in[2];

  unsigned short* s_h = (unsigned short*)d_ws;                    // 8 MB
  unsigned short* cand_h = s_h + (size_t)N_ROWS * D_DIM;          // 16 MB
  float* rowsum = (float*)(cand_h + (size_t)N_CAND * D_DIM);      // 16 KB
  float* pos = rowsum + N_ROWS;                                   // 16 KB
  float* out = (float*)d_out;

  prep_kernel<<<dim3(3 * N_ROWS), dim3(256), 0, stream>>>(s, p, ng, s_h,
                                                          cand_h, rowsum);
  gemm_lse_kernel<<<dim3(N_CAND / BN, N_ROWS / BM), dim3(512), 0, stream>>>(
      s_h, cand_h, rowsum, pos);
  loss_kernel<<<dim3(1), dim3(1024), 0, stream>>>(rowsum, pos, out);
}